// Round 10
// baseline (131.566 us; speedup 1.0000x reference)
//
#include <hip/hip_runtime.h>
#include <hip/hip_bf16.h>
#include <hip/hip_cooperative_groups.h>

namespace cg = cooperative_groups;

// Problem constants
#define M_ROWS   1792                 // 7 * 256 softpool rows
#define KDIM     512
#define OUT_FEAT_SZ (M_ROWS*1024)     // 1835008
#define OUT_HAT_SZ  (M_ROWS*512)      // 917504

typedef __attribute__((ext_vector_type(8))) __bf16 bf16x8;
typedef __attribute__((ext_vector_type(4))) float  f32x4;

__device__ __forceinline__ unsigned short f2bf(float f) {
    union { float f; unsigned int u; } v; v.f = f;
    unsigned int r = v.u + 0x7fffu + ((v.u >> 16) & 1u);   // RNE
    return (unsigned short)(r >> 16);
}

__device__ __forceinline__ void load_lds16(const float* g, float* l) {
    __builtin_amdgcn_global_load_lds(
        (const __attribute__((address_space(1))) void*)g,
        (__attribute__((address_space(3))) void*)l, 16, 0, 0);
}

// Single cooperative kernel.
// Phase A (512 blocks): weight cvt + softpool b-column stream (triple-buffered
//   global_load_lds, counted vmcnt). Block bx: side=bx&1, lp=bx>>1.
// grid.sync()
// Phase B (448 blocks): fc2 GEMM on 8-row tiles + bias + residual + softmax
//   + concat. Job: side=bx&1, tile=bx>>1 (0..223), mbase=tile*8 (<=1784).
//   (R9 bug was 16-row tiles with 448 jobs -> mbase up to 3568 -> OOB.)
__global__ __launch_bounds__(512, 4) void coop_k(
    const float* __restrict__ x, const float* __restrict__ y,
    const float* __restrict__ wv, const float* __restrict__ wt,
    const float* __restrict__ bv, const float* __restrict__ bt,
    const float* __restrict__ wvec,
    float* __restrict__ xsp, float* __restrict__ ysp,
    unsigned short* __restrict__ wvb, unsigned short* __restrict__ wtb,
    float* __restrict__ d_out)
{
    __shared__ union SH {
        float bufA[3][2048];                           // 3 x 8 KB plane chunks
        struct { unsigned short tA[8*520]; float resl[8*516]; } g;
    } sh;

    const int bx  = blockIdx.x;       // 0..511
    const int tid = threadIdx.x;      // 0..511
    const int side = bx & 1;
    const int lp   = bx >> 1;         // l' 0..255

    // ---- phase A0: weight f32->bf16 cvt (1 elem per matrix per thread)
    {
        int idx = bx * 512 + tid;     // 0..262143 == 512*512 exactly
        wvb[idx] = f2bf(wv[idx]);
        wtb[idx] = f2bf(wt[idx]);
    }
    // drain cvt loads/stores so counted vmcnt below sees only our glls
    asm volatile("s_waitcnt vmcnt(0)" ::: "memory");

    // ---- phase A1: softpool b-column stream
    const float* in  = side ? y   : x;
    float*       out = side ? ysp : xsp;
    const int w    = tid >> 6;        // wave 0..7
    const int lane = tid & 63;

    // wave w stages l-row (w>>2), segment (w&3) of plane p: 64 lanes x 16 B
#define STAGE(p, c) { \
    const float* g0 = in + ((size_t)((p)*512 + 2*lp + (w>>2)))*1024 + (w&3)*256 + lane*4; \
    load_lds16(g0, &sh.bufA[c][(w>>2)*1024 + (w&3)*256]); }

    float num[7], den[7];
    #pragma unroll
    for (int b = 0; b < 7; ++b) { num[b]=0.f; den[b]=0.f; }

    STAGE(0, 0)
    STAGE(1, 1)

    #pragma unroll
    for (int p = 0; p < 16; ++p) {
        if (p < 14) {
            STAGE(p + 2, (p + 2) % 3)
            asm volatile("s_waitcnt vmcnt(2)" ::: "memory");   // plane p landed
        } else if (p == 14) {
            asm volatile("s_waitcnt vmcnt(1)" ::: "memory");
        } else {
            asm volatile("s_waitcnt vmcnt(0)" ::: "memory");
        }
        __builtin_amdgcn_s_barrier();
        __builtin_amdgcn_sched_barrier(0);

        const int c = p % 3;
        float2 a  = *reinterpret_cast<const float2*>(&sh.bufA[c][2*tid]);        // row 2lp
        float2 b2 = *reinterpret_cast<const float2*>(&sh.bufA[c][1024 + 2*tid]); // row 2lp+1
        float e0=__expf(a.x),  e1=__expf(a.y);
        float e2=__expf(b2.x), e3=__expf(b2.y);
        float n = e0*a.x + e1*a.y + e2*b2.x + e3*b2.y;
        float d = (e0+e1) + (e2+e3);
        // plane p feeds windows b' = p/2 (taps 0/1) and p/2 - 1 (taps 2/3)
        const int bh = p >> 1, bl = bh - 1;
        if (bh <= 6) { num[bh] += n; den[bh] += d; }
        if (bl >= 0) { num[bl] += n; den[bl] += d; }

        __builtin_amdgcn_s_barrier();      // protect buf[c] before restage
        __builtin_amdgcn_sched_barrier(0);
    }
#undef STAGE

    // epilogue: thread owns d' = tid; 7 coalesced scalar stores
    {
        float* outp = out + (size_t)lp*512 + tid;
        #pragma unroll
        for (int b = 0; b < 7; ++b)
            outp[(size_t)b*131072] = num[b]/den[b];
    }

    // ---- grid-wide barrier (device-scope fence: xsp/ysp/wvb/wtb visible)
    cg::this_grid().sync();

    // ---- phase B: fc2 GEMM + softmax, 8-row tiles (448 jobs)
    if (bx < 448) {
        const int side2 = bx & 1;
        const int tile  = bx >> 1;          // 0..223
        const float* A          = side2 ? ysp : xsp;
        const unsigned short* B = side2 ? wtb : wvb;
        const float* bias       = side2 ? bt  : bv;
        const int mbase = tile * 8;         // <= 1784

        // stage A tile: 8x512 f32 -> {bf16 tA, f32 resl}; 1024 float4s
        {
            const float* Ab = A + (size_t)mbase * KDIM;
            #pragma unroll
            for (int rr = 0; rr < 2; ++rr) {
                int f4  = tid + rr*512;       // 0..1023
                float4 v = reinterpret_cast<const float4*>(Ab)[f4];
                int row = f4 >> 7;            // 0..7
                int col = (f4 & 127) << 2;
                ushort4 o; o.x=f2bf(v.x); o.y=f2bf(v.y); o.z=f2bf(v.z); o.w=f2bf(v.w);
                *reinterpret_cast<ushort4*>(&sh.g.tA[row*520 + col]) = o;
                *reinterpret_cast<float4*>(&sh.g.resl[row*516 + col]) = v;
            }
        }
        __syncthreads();

        const int arow = lane & 15;
        const int kq   = lane >> 4;     // 0..3
        const int nb   = w * 64;        // wave w owns cols [w*64, w*64+64)

        f32x4 acc0 = (f32x4){0.f,0.f,0.f,0.f};
        f32x4 acc1 = (f32x4){0.f,0.f,0.f,0.f};
        f32x4 acc2 = (f32x4){0.f,0.f,0.f,0.f};
        f32x4 acc3 = (f32x4){0.f,0.f,0.f,0.f};

        const unsigned short* B0 = B + (size_t)(nb      + arow) * KDIM + kq*8;
        const unsigned short* B1 = B + (size_t)(nb + 16 + arow) * KDIM + kq*8;
        const unsigned short* B2 = B + (size_t)(nb + 32 + arow) * KDIM + kq*8;
        const unsigned short* B3 = B + (size_t)(nb + 48 + arow) * KDIM + kq*8;
        bf16x8 c0 = *reinterpret_cast<const bf16x8*>(B0);
        bf16x8 c1 = *reinterpret_cast<const bf16x8*>(B1);
        bf16x8 c2 = *reinterpret_cast<const bf16x8*>(B2);
        bf16x8 c3 = *reinterpret_cast<const bf16x8*>(B3);
        bf16x8 n0 = *reinterpret_cast<const bf16x8*>(B0 + 32);
        bf16x8 n1 = *reinterpret_cast<const bf16x8*>(B1 + 32);
        bf16x8 n2 = *reinterpret_cast<const bf16x8*>(B2 + 32);
        bf16x8 n3 = *reinterpret_cast<const bf16x8*>(B3 + 32);

        #pragma unroll
        for (int ks = 0; ks < 16; ++ks) {
            // A rows 8-15 duplicate rows 0-7 (arow&7); garbage C-rows discarded
            bf16x8 af = *reinterpret_cast<const bf16x8*>(&sh.g.tA[(arow & 7)*520 + ks*32 + kq*8]);
            acc0 = __builtin_amdgcn_mfma_f32_16x16x32_bf16(af, c0, acc0, 0, 0, 0);
            acc1 = __builtin_amdgcn_mfma_f32_16x16x32_bf16(af, c1, acc1, 0, 0, 0);
            acc2 = __builtin_amdgcn_mfma_f32_16x16x32_bf16(af, c2, acc2, 0, 0, 0);
            acc3 = __builtin_amdgcn_mfma_f32_16x16x32_bf16(af, c3, acc3, 0, 0, 0);
            c0 = n0; c1 = n1; c2 = n2; c3 = n3;
            if (ks < 14) {
                n0 = *reinterpret_cast<const bf16x8*>(B0 + (ks+2)*32);
                n1 = *reinterpret_cast<const bf16x8*>(B1 + (ks+2)*32);
                n2 = *reinterpret_cast<const bf16x8*>(B2 + (ks+2)*32);
                n3 = *reinterpret_cast<const bf16x8*>(B3 + (ks+2)*32);
            }
        }

        // epilogue: logits = acc + bias (+ residual side 0); rows 0..7 only
        if (kq < 2) {
            #pragma unroll
            for (int t = 0; t < 4; ++t) {
                f32x4 a = t==0 ? acc0 : t==1 ? acc1 : t==2 ? acc2 : acc3;
                int n = nb + t*16 + arow;
                float bn = bias[n];
                #pragma unroll
                for (int i = 0; i < 4; ++i) {
                    int row = kq*4 + i;    // C/D: col=lane&15, row=(lane>>4)*4+i
                    float vv = a[i] + bn;
                    if (side2 == 0) vv += sh.g.resl[row*516 + n];
                    sh.g.resl[row*516 + n] = vv;
                }
            }
        }
        __syncthreads();

        // softmax: wave w handles row w (0..7), full 512 cols, 8 per lane
        float ew0 = __expf(wvec[0]), ew1 = __expf(wvec[1]);
        float wsc = (side2 ? ew1 : ew0) / (ew0 + ew1);
        float* feat = d_out;
        float* hat  = d_out + OUT_FEAT_SZ + (size_t)side2 * OUT_HAT_SZ;

        {
            int m = mbase + w;
            const float* lpp = &sh.g.resl[w*516 + lane*8];
            float4 v0 = *reinterpret_cast<const float4*>(lpp);
            float4 v1 = *reinterpret_cast<const float4*>(lpp + 4);
            float mx = fmaxf(fmaxf(fmaxf(v0.x,v0.y), fmaxf(v0.z,v0.w)),
                             fmaxf(fmaxf(v1.x,v1.y), fmaxf(v1.z,v1.w)));
            #pragma unroll
            for (int s = 32; s; s >>= 1) mx = fmaxf(mx, __shfl_xor(mx, s));
            float e0=__expf(v0.x-mx), e1=__expf(v0.y-mx), e2=__expf(v0.z-mx), e3=__expf(v0.w-mx);
            float e4=__expf(v1.x-mx), e5=__expf(v1.y-mx), e6=__expf(v1.z-mx), e7=__expf(v1.w-mx);
            float sum = ((e0+e1)+(e2+e3)) + ((e4+e5)+(e6+e7));
            #pragma unroll
            for (int s = 32; s; s >>= 1) sum += __shfl_xor(sum, s);
            float inv = 1.f / sum;
            float4 p0 = {e0*inv, e1*inv, e2*inv, e3*inv};
            float4 p1 = {e4*inv, e5*inv, e6*inv, e7*inv};
            *reinterpret_cast<float4*>(&hat[(size_t)m*512 + lane*8])     = p0;
            *reinterpret_cast<float4*>(&hat[(size_t)m*512 + lane*8 + 4]) = p1;
            float4 f0 = {p0.x*wsc, p0.y*wsc, p0.z*wsc, p0.w*wsc};
            float4 f1 = {p1.x*wsc, p1.y*wsc, p1.z*wsc, p1.w*wsc};
            size_t fo = (size_t)m*1024 + side2*512 + lane*8;
            *reinterpret_cast<float4*>(&feat[fo])     = f0;
            *reinterpret_cast<float4*>(&feat[fo + 4]) = f1;
        }
    }
}

extern "C" void kernel_launch(void* const* d_in, const int* in_sizes, int n_in,
                              void* d_out, int out_size, void* d_ws, size_t ws_size,
                              hipStream_t stream)
{
    const float* x       = (const float*)d_in[0];
    const float* y       = (const float*)d_in[1];
    const float* w_fc2_t = (const float*)d_in[12];
    const float* b_fc2_t = (const float*)d_in[13];
    const float* w_fc2_v = (const float*)d_in[14];
    const float* b_fc2_v = (const float*)d_in[15];
    const float* wvec    = (const float*)d_in[18];

    float* xsp = (float*)d_ws;                       // 917504 f32
    float* ysp = xsp + 917504;                       // 917504 f32
    unsigned short* wvb = (unsigned short*)(ysp + 917504);  // 262144 bf16
    unsigned short* wtb = wvb + 262144;              // 262144 bf16
    float* out = (float*)d_out;

    void* args[] = { (void*)&x, (void*)&y, (void*)&w_fc2_v, (void*)&w_fc2_t,
                     (void*)&b_fc2_v, (void*)&b_fc2_t, (void*)&wvec,
                     (void*)&xsp, (void*)&ysp, (void*)&wvb, (void*)&wtb,
                     (void*)&out };
    hipLaunchCooperativeKernel(coop_k, dim3(512), dim3(512), args, 0, stream);
}

// Round 11
// 51.959 us; speedup vs baseline: 2.5321x; 2.5321x over previous
//
#include <hip/hip_runtime.h>
#include <hip/hip_bf16.h>

// Problem constants
#define M_ROWS   1792                 // 7 * 256 softpool rows
#define KDIM     512
#define OUT_FEAT_SZ (M_ROWS*1024)     // 1835008
#define OUT_HAT_SZ  (M_ROWS*512)      // 917504

typedef __attribute__((ext_vector_type(8))) __bf16 bf16x8;
typedef __attribute__((ext_vector_type(4))) float  f32x4;
typedef __attribute__((ext_vector_type(8))) unsigned short ushort8v;

__device__ __forceinline__ unsigned short f2bf(float f) {
    union { float f; unsigned int u; } v; v.f = f;
    unsigned int r = v.u + 0x7fffu + ((v.u >> 16) & 1u);   // RNE
    return (unsigned short)(r >> 16);
}

// K1 (R5-exact, best measured): softpool3d rows (blocks 0..1791) + weight
// f32->bf16 cvt (blocks 1792..1919). blockIdx.y = tensor side.
__global__ __launch_bounds__(256) void sp_k(
    const float* __restrict__ x, const float* __restrict__ y,
    const float* __restrict__ wv, const float* __restrict__ wt,
    float* __restrict__ xsp, float* __restrict__ ysp,
    unsigned short* __restrict__ wvb, unsigned short* __restrict__ wtb)
{
    const int side = blockIdx.y;
    if (blockIdx.x >= M_ROWS) {
        // ---- weight cvt: 128 blocks x 256 thr x 8 elems = 262144
        int blk = blockIdx.x - M_ROWS;
        const float* s = side ? wt : wv;
        unsigned short* d = side ? wtb : wvb;
        int i = (blk * 256 + threadIdx.x) * 8;
        float4 v0 = *reinterpret_cast<const float4*>(s + i);
        float4 v1 = *reinterpret_cast<const float4*>(s + i + 4);
        ushort8v o;
        o[0]=f2bf(v0.x); o[1]=f2bf(v0.y); o[2]=f2bf(v0.z); o[3]=f2bf(v0.w);
        o[4]=f2bf(v1.x); o[5]=f2bf(v1.y); o[6]=f2bf(v1.z); o[7]=f2bf(v1.w);
        *reinterpret_cast<ushort8v*>(d + i) = o;
        return;
    }
    const float* in  = side ? y   : x;
    float*       out = side ? ysp : xsp;
    const int r  = blockIdx.x;
    const int bp = r >> 8;        // b' 0..6
    const int lp = r & 255;       // l'
    const int u  = threadIdx.x;   // d' pair

    const float* base = in + ((size_t)(2*bp) * 512 + 2*lp) * 1024 + 4*u;
    float4 v[8];
    #pragma unroll
    for (int i = 0; i < 4; ++i)
        #pragma unroll
        for (int j = 0; j < 2; ++j)
            v[i*2+j] = *reinterpret_cast<const float4*>(base + ((size_t)(i*512 + j))*1024);
    __builtin_amdgcn_sched_group_barrier(0x20, 8, 0);   // cluster the 8 reads

    float num0=0.f, den0=0.f, num1=0.f, den1=0.f;
    #pragma unroll
    for (int k = 0; k < 8; ++k) {
        float e0=__expf(v[k].x), e1=__expf(v[k].y), e2=__expf(v[k].z), e3=__expf(v[k].w);
        num0 += e0*v[k].x + e1*v[k].y;  den0 += e0 + e1;
        num1 += e2*v[k].z + e3*v[k].w;  den1 += e2 + e3;
    }
    *reinterpret_cast<float2*>(out + (size_t)r*512 + 2*u) =
        make_float2(num0/den0, num1/den1);
}

// K2: fc2 GEMM + bias (+ residual side 0) + row-softmax + concat.
// 8-row tiles -> 224 tiles/side -> 448 blocks (1.75/CU: fixes the 224-block
// half-idle GEMM phase of R5). 512 thr / 8 waves; wave w owns cols
// [w*64, w*64+64) via 4 B-streams, register-double-buffered 2 ks ahead.
// A rows 8-15 of the MFMA duplicate rows 0-7 (arow&7); garbage C discarded
// by the kq<2 epilogue predicate (R4-verified pattern).
__global__ __launch_bounds__(512, 2) void gemm_sm_k(
    const float* __restrict__ xsp, const float* __restrict__ ysp,
    const unsigned short* __restrict__ wvb, const unsigned short* __restrict__ wtb,
    const float* __restrict__ bv, const float* __restrict__ bt,
    const float* __restrict__ wvec, float* __restrict__ d_out)
{
    const int side = blockIdx.y;
    const float* A           = side ? ysp : xsp;
    const unsigned short* B  = side ? wtb : wvb;
    const float* bias        = side ? bt  : bv;
    const int mbase = blockIdx.x * 8;    // 0..1784

    __shared__ unsigned short tA[8 * 520];   // bf16 A tile, padded
    __shared__ float resl[8 * 516];          // f32 A copy (residual) -> logits

    const int tid = threadIdx.x;

    // ---- stage A: 8x512 f32 -> {bf16 tA, f32 resl}; 1024 float4s
    {
        const float* Ab = A + (size_t)mbase * KDIM;
        #pragma unroll
        for (int rr = 0; rr < 2; ++rr) {
            int f4  = tid + rr*512;          // 0..1023
            float4 v = reinterpret_cast<const float4*>(Ab)[f4];
            int row = f4 >> 7;               // 0..7
            int col = (f4 & 127) << 2;
            ushort4 o; o.x=f2bf(v.x); o.y=f2bf(v.y); o.z=f2bf(v.z); o.w=f2bf(v.w);
            *reinterpret_cast<ushort4*>(&tA[row*520 + col]) = o;
            *reinterpret_cast<float4*>(&resl[row*516 + col]) = v;
        }
    }
    __syncthreads();

    const int lane = tid & 63;
    const int w    = tid >> 6;       // 0..7
    const int arow = lane & 15;
    const int kq   = lane >> 4;      // 0..3
    const int nb   = w * 64;

    f32x4 acc0 = (f32x4){0.f,0.f,0.f,0.f};
    f32x4 acc1 = (f32x4){0.f,0.f,0.f,0.f};
    f32x4 acc2 = (f32x4){0.f,0.f,0.f,0.f};
    f32x4 acc3 = (f32x4){0.f,0.f,0.f,0.f};

    const unsigned short* B0 = B + (size_t)(nb      + arow) * KDIM + kq*8;
    const unsigned short* B1 = B + (size_t)(nb + 16 + arow) * KDIM + kq*8;
    const unsigned short* B2 = B + (size_t)(nb + 32 + arow) * KDIM + kq*8;
    const unsigned short* B3 = B + (size_t)(nb + 48 + arow) * KDIM + kq*8;
    bf16x8 c0 = *reinterpret_cast<const bf16x8*>(B0);
    bf16x8 c1 = *reinterpret_cast<const bf16x8*>(B1);
    bf16x8 c2 = *reinterpret_cast<const bf16x8*>(B2);
    bf16x8 c3 = *reinterpret_cast<const bf16x8*>(B3);
    bf16x8 n0 = *reinterpret_cast<const bf16x8*>(B0 + 32);
    bf16x8 n1 = *reinterpret_cast<const bf16x8*>(B1 + 32);
    bf16x8 n2 = *reinterpret_cast<const bf16x8*>(B2 + 32);
    bf16x8 n3 = *reinterpret_cast<const bf16x8*>(B3 + 32);

    #pragma unroll
    for (int ks = 0; ks < 16; ++ks) {
        bf16x8 af = *reinterpret_cast<const bf16x8*>(&tA[(arow & 7)*520 + ks*32 + kq*8]);
        acc0 = __builtin_amdgcn_mfma_f32_16x16x32_bf16(af, c0, acc0, 0, 0, 0);
        acc1 = __builtin_amdgcn_mfma_f32_16x16x32_bf16(af, c1, acc1, 0, 0, 0);
        acc2 = __builtin_amdgcn_mfma_f32_16x16x32_bf16(af, c2, acc2, 0, 0, 0);
        acc3 = __builtin_amdgcn_mfma_f32_16x16x32_bf16(af, c3, acc3, 0, 0, 0);
        c0 = n0; c1 = n1; c2 = n2; c3 = n3;
        if (ks < 14) {
            n0 = *reinterpret_cast<const bf16x8*>(B0 + (ks+2)*32);
            n1 = *reinterpret_cast<const bf16x8*>(B1 + (ks+2)*32);
            n2 = *reinterpret_cast<const bf16x8*>(B2 + (ks+2)*32);
            n3 = *reinterpret_cast<const bf16x8*>(B3 + (ks+2)*32);
        }
    }

    // ---- epilogue: logits = acc + bias (+ residual side 0); rows 0..7 only
    if (kq < 2) {
        #pragma unroll
        for (int t = 0; t < 4; ++t) {
            f32x4 a = t==0 ? acc0 : t==1 ? acc1 : t==2 ? acc2 : acc3;
            int n = nb + t*16 + arow;
            float bn = bias[n];
            #pragma unroll
            for (int i = 0; i < 4; ++i) {
                int row = kq*4 + i;    // C/D: col=lane&15, row=(lane>>4)*4+i
                float vv = a[i] + bn;
                if (side == 0) vv += resl[row*516 + n];
                resl[row*516 + n] = vv;
            }
        }
    }
    __syncthreads();

    // ---- softmax: wave w handles row w (0..7), full 512 cols, 8 per lane
    float ew0 = __expf(wvec[0]), ew1 = __expf(wvec[1]);
    float wsc = (side ? ew1 : ew0) / (ew0 + ew1);
    float* feat = d_out;
    float* hat  = d_out + OUT_FEAT_SZ + (size_t)side * OUT_HAT_SZ;

    {
        int m = mbase + w;
        const float* lpp = &resl[w*516 + lane*8];
        float4 v0 = *reinterpret_cast<const float4*>(lpp);
        float4 v1 = *reinterpret_cast<const float4*>(lpp + 4);
        float mx = fmaxf(fmaxf(fmaxf(v0.x,v0.y), fmaxf(v0.z,v0.w)),
                         fmaxf(fmaxf(v1.x,v1.y), fmaxf(v1.z,v1.w)));
        #pragma unroll
        for (int s = 32; s; s >>= 1) mx = fmaxf(mx, __shfl_xor(mx, s));
        float e0=__expf(v0.x-mx), e1=__expf(v0.y-mx), e2=__expf(v0.z-mx), e3=__expf(v0.w-mx);
        float e4=__expf(v1.x-mx), e5=__expf(v1.y-mx), e6=__expf(v1.z-mx), e7=__expf(v1.w-mx);
        float sum = ((e0+e1)+(e2+e3)) + ((e4+e5)+(e6+e7));
        #pragma unroll
        for (int s = 32; s; s >>= 1) sum += __shfl_xor(sum, s);
        float inv = 1.f / sum;
        float4 p0 = {e0*inv, e1*inv, e2*inv, e3*inv};
        float4 p1 = {e4*inv, e5*inv, e6*inv, e7*inv};
        *reinterpret_cast<float4*>(&hat[(size_t)m*512 + lane*8])     = p0;
        *reinterpret_cast<float4*>(&hat[(size_t)m*512 + lane*8 + 4]) = p1;
        float4 f0 = {p0.x*wsc, p0.y*wsc, p0.z*wsc, p0.w*wsc};
        float4 f1 = {p1.x*wsc, p1.y*wsc, p1.z*wsc, p1.w*wsc};
        size_t fo = (size_t)m*1024 + side*512 + lane*8;
        *reinterpret_cast<float4*>(&feat[fo])     = f0;
        *reinterpret_cast<float4*>(&feat[fo + 4]) = f1;
    }
}

extern "C" void kernel_launch(void* const* d_in, const int* in_sizes, int n_in,
                              void* d_out, int out_size, void* d_ws, size_t ws_size,
                              hipStream_t stream)
{
    const float* x        = (const float*)d_in[0];
    const float* y        = (const float*)d_in[1];
    const float* w_fc2_t  = (const float*)d_in[12];
    const float* b_fc2_t  = (const float*)d_in[13];
    const float* w_fc2_v  = (const float*)d_in[14];
    const float* b_fc2_v  = (const float*)d_in[15];
    const float* wvec     = (const float*)d_in[18];

    float* xsp = (float*)d_ws;                       // 917504 f32
    float* ysp = xsp + 917504;                       // 917504 f32
    unsigned short* wvb = (unsigned short*)(ysp + 917504);  // 262144 bf16
    unsigned short* wtb = wvb + 262144;              // 262144 bf16

    // 1) softpool (row formulation, R5-exact) + weight cvt, one launch
    sp_k<<<dim3(M_ROWS + 128, 2), 256, 0, stream>>>(
        x, y, w_fc2_v, w_fc2_t, xsp, ysp, wvb, wtb);
    // 2) fused fc2 + residual + softmax + concat, 8-row tiles / 448 blocks
    gemm_sm_k<<<dim3(M_ROWS/8, 2), 512, 0, stream>>>(
        xsp, ysp, wvb, wtb, b_fc2_v, b_fc2_t, wvec, (float*)d_out);
}

// Round 12
// 38.653 us; speedup vs baseline: 3.4038x; 1.3442x over previous
//
#include <hip/hip_runtime.h>
#include <hip/hip_bf16.h>

// Problem constants
#define M_ROWS   1792                 // 7 * 256 softpool rows
#define KDIM     512
#define OUT_FEAT_SZ (M_ROWS*1024)     // 1835008
#define OUT_HAT_SZ  (M_ROWS*512)      // 917504

typedef __attribute__((ext_vector_type(8))) __bf16 bf16x8;
typedef __attribute__((ext_vector_type(4))) float  f32x4;
typedef __attribute__((ext_vector_type(8))) unsigned short ushort8v;

__device__ __forceinline__ unsigned short f2bf(float f) {
    union { float f; unsigned int u; } v; v.f = f;
    unsigned int r = v.u + 0x7fffu + ((v.u >> 16) & 1u);   // RNE
    return (unsigned short)(r >> 16);
}

// K1 (best measured, R5): softpool3d rows (blocks 0..1791) + weight f32->bf16
// cvt (blocks 1792..1919). blockIdx.y = tensor side.
// Softpool: 1 output row per block; thread u owns d' pair (2u,2u+1); the 8
// float4 taps are issued as one clustered burst (sched_group_barrier).
__global__ __launch_bounds__(256) void sp_k(
    const float* __restrict__ x, const float* __restrict__ y,
    const float* __restrict__ wv, const float* __restrict__ wt,
    float* __restrict__ xsp, float* __restrict__ ysp,
    unsigned short* __restrict__ wvb, unsigned short* __restrict__ wtb)
{
    const int side = blockIdx.y;
    if (blockIdx.x >= M_ROWS) {
        // ---- weight cvt: 128 blocks x 256 thr x 8 elems = 262144
        int blk = blockIdx.x - M_ROWS;
        const float* s = side ? wt : wv;
        unsigned short* d = side ? wtb : wvb;
        int i = (blk * 256 + threadIdx.x) * 8;
        float4 v0 = *reinterpret_cast<const float4*>(s + i);
        float4 v1 = *reinterpret_cast<const float4*>(s + i + 4);
        ushort8v o;
        o[0]=f2bf(v0.x); o[1]=f2bf(v0.y); o[2]=f2bf(v0.z); o[3]=f2bf(v0.w);
        o[4]=f2bf(v1.x); o[5]=f2bf(v1.y); o[6]=f2bf(v1.z); o[7]=f2bf(v1.w);
        *reinterpret_cast<ushort8v*>(d + i) = o;
        return;
    }
    const float* in  = side ? y   : x;
    float*       out = side ? ysp : xsp;
    const int r  = blockIdx.x;
    const int bp = r >> 8;        // b' 0..6
    const int lp = r & 255;       // l'
    const int u  = threadIdx.x;   // d' pair

    const float* base = in + ((size_t)(2*bp) * 512 + 2*lp) * 1024 + 4*u;
    float4 v[8];
    #pragma unroll
    for (int i = 0; i < 4; ++i)
        #pragma unroll
        for (int j = 0; j < 2; ++j)
            v[i*2+j] = *reinterpret_cast<const float4*>(base + ((size_t)(i*512 + j))*1024);
    // pin: all 8 VMEM reads scheduled before the compute burst
    __builtin_amdgcn_sched_group_barrier(0x20, 8, 0);

    float num0=0.f, den0=0.f, num1=0.f, den1=0.f;
    #pragma unroll
    for (int k = 0; k < 8; ++k) {
        float e0=__expf(v[k].x), e1=__expf(v[k].y), e2=__expf(v[k].z), e3=__expf(v[k].w);
        num0 += e0*v[k].x + e1*v[k].y;  den0 += e0 + e1;
        num1 += e2*v[k].z + e3*v[k].w;  den1 += e2 + e3;
    }
    *reinterpret_cast<float2*>(out + (size_t)r*512 + 2*u) =
        make_float2(num0/den0, num1/den1);
}

// K2 (best measured, R5): C = A @ W^T + bias (+ residual A, side 0),
// row-softmax N=512, write hat + scaled feature half. 16-row tiles
// (224 blocks/side: minimal B re-read, B L2-resident), 1024 thr / 16 waves;
// wave w owns cols [w*32,w*32+32); B register-double-buffered 2 ks ahead.
__global__ __launch_bounds__(1024) void gemm_sm_k(
    const float* __restrict__ xsp, const float* __restrict__ ysp,
    const unsigned short* __restrict__ wvb, const unsigned short* __restrict__ wtb,
    const float* __restrict__ bv, const float* __restrict__ bt,
    const float* __restrict__ wvec, float* __restrict__ d_out)
{
    const int side = blockIdx.y;
    const float* A           = side ? ysp : xsp;
    const unsigned short* B  = side ? wtb : wvb;
    const float* bias        = side ? bt  : bv;
    const int mbase = blockIdx.x * 16;

    __shared__ unsigned short tA[16 * 520];  // bf16 A tile, padded
    __shared__ float resl[16 * 516];         // f32 A copy (residual) -> logits

    const int tid = threadIdx.x;

    // ---- stage A: 16x512 f32 -> {bf16 tA, f32 resl}
    {
        const float* Ab = A + (size_t)mbase * KDIM;
        #pragma unroll
        for (int rr = 0; rr < 2; ++rr) {
            int f4  = tid + rr*1024;           // 0..2047
            float4 v = reinterpret_cast<const float4*>(Ab)[f4];
            int row = f4 >> 7;
            int col = (f4 & 127) << 2;
            ushort4 o; o.x=f2bf(v.x); o.y=f2bf(v.y); o.z=f2bf(v.z); o.w=f2bf(v.w);
            *reinterpret_cast<ushort4*>(&tA[row*520 + col]) = o;
            *reinterpret_cast<float4*>(&resl[row*516 + col]) = v;
        }
    }
    __syncthreads();

    const int lane = tid & 63;
    const int w    = tid >> 6;       // 0..15
    const int arow = lane & 15;
    const int kq   = lane >> 4;      // 0..3
    const int nb   = w * 32;

    f32x4 acc0 = (f32x4){0.f,0.f,0.f,0.f};
    f32x4 acc1 = (f32x4){0.f,0.f,0.f,0.f};

    const unsigned short* B0 = B + (size_t)(nb      + arow) * KDIM + kq*8;
    const unsigned short* B1 = B + (size_t)(nb + 16 + arow) * KDIM + kq*8;
    bf16x8 b0a = *reinterpret_cast<const bf16x8*>(B0);
    bf16x8 b1a = *reinterpret_cast<const bf16x8*>(B1);
    bf16x8 b0b = *reinterpret_cast<const bf16x8*>(B0 + 32);
    bf16x8 b1b = *reinterpret_cast<const bf16x8*>(B1 + 32);

    #pragma unroll
    for (int ks = 0; ks < 16; ++ks) {
        bf16x8 af = *reinterpret_cast<const bf16x8*>(&tA[arow*520 + ks*32 + kq*8]);
        bf16x8 c0 = b0a, c1 = b1a;
        b0a = b0b; b1a = b1b;
        if (ks < 14) {
            b0b = *reinterpret_cast<const bf16x8*>(B0 + (ks+2)*32);
            b1b = *reinterpret_cast<const bf16x8*>(B1 + (ks+2)*32);
        }
        acc0 = __builtin_amdgcn_mfma_f32_16x16x32_bf16(af, c0, acc0, 0, 0, 0);
        acc1 = __builtin_amdgcn_mfma_f32_16x16x32_bf16(af, c1, acc1, 0, 0, 0);
    }

    // ---- epilogue: logits = acc + bias (+ residual side 0), in-place
    #pragma unroll
    for (int t = 0; t < 2; ++t) {
        int n = nb + t*16 + arow;
        float bn = bias[n];
        f32x4 a = t ? acc1 : acc0;
        #pragma unroll
        for (int i = 0; i < 4; ++i) {
            int row = kq*4 + i;    // C/D: col=lane&15, row=(lane>>4)*4+i
            float vv = a[i] + bn;
            if (side == 0) vv += resl[row*516 + n];
            resl[row*516 + n] = vv;
        }
    }
    __syncthreads();

    // ---- softmax: wave w handles row w (full 512 cols, 8 per lane)
    float ew0 = __expf(wvec[0]), ew1 = __expf(wvec[1]);
    float wsc = (side ? ew1 : ew0) / (ew0 + ew1);
    float* feat = d_out;
    float* hat  = d_out + OUT_FEAT_SZ + (size_t)side * OUT_HAT_SZ;

    {
        int m = mbase + w;
        const float* lp = &resl[w*516 + lane*8];
        float4 v0 = *reinterpret_cast<const float4*>(lp);
        float4 v1 = *reinterpret_cast<const float4*>(lp + 4);
        float mx = fmaxf(fmaxf(fmaxf(v0.x,v0.y), fmaxf(v0.z,v0.w)),
                         fmaxf(fmaxf(v1.x,v1.y), fmaxf(v1.z,v1.w)));
        #pragma unroll
        for (int s = 32; s; s >>= 1) mx = fmaxf(mx, __shfl_xor(mx, s));
        float e0=__expf(v0.x-mx), e1=__expf(v0.y-mx), e2=__expf(v0.z-mx), e3=__expf(v0.w-mx);
        float e4=__expf(v1.x-mx), e5=__expf(v1.y-mx), e6=__expf(v1.z-mx), e7=__expf(v1.w-mx);
        float sum = ((e0+e1)+(e2+e3)) + ((e4+e5)+(e6+e7));
        #pragma unroll
        for (int s = 32; s; s >>= 1) sum += __shfl_xor(sum, s);
        float inv = 1.f / sum;
        float4 p0 = {e0*inv, e1*inv, e2*inv, e3*inv};
        float4 p1 = {e4*inv, e5*inv, e6*inv, e7*inv};
        *reinterpret_cast<float4*>(&hat[(size_t)m*512 + lane*8])     = p0;
        *reinterpret_cast<float4*>(&hat[(size_t)m*512 + lane*8 + 4]) = p1;
        float4 f0 = {p0.x*wsc, p0.y*wsc, p0.z*wsc, p0.w*wsc};
        float4 f1 = {p1.x*wsc, p1.y*wsc, p1.z*wsc, p1.w*wsc};
        size_t fo = (size_t)m*1024 + side*512 + lane*8;
        *reinterpret_cast<float4*>(&feat[fo])     = f0;
        *reinterpret_cast<float4*>(&feat[fo + 4]) = f1;
    }
}

extern "C" void kernel_launch(void* const* d_in, const int* in_sizes, int n_in,
                              void* d_out, int out_size, void* d_ws, size_t ws_size,
                              hipStream_t stream)
{
    const float* x        = (const float*)d_in[0];
    const float* y        = (const float*)d_in[1];
    const float* w_fc2_t  = (const float*)d_in[12];
    const float* b_fc2_t  = (const float*)d_in[13];
    const float* w_fc2_v  = (const float*)d_in[14];
    const float* b_fc2_v  = (const float*)d_in[15];
    const float* wvec     = (const float*)d_in[18];

    float* xsp = (float*)d_ws;                       // 917504 f32
    float* ysp = xsp + 917504;                       // 917504 f32
    unsigned short* wvb = (unsigned short*)(ysp + 917504);  // 262144 bf16
    unsigned short* wtb = wvb + 262144;              // 262144 bf16

    // 1) softpool (row formulation) + weight cvt, one launch
    sp_k<<<dim3(M_ROWS + 128, 2), 256, 0, stream>>>(
        x, y, w_fc2_v, w_fc2_t, xsp, ysp, wvb, wtb);
    // 2) fused fc2 + residual + softmax + concat (16-row tiles, 16 waves)
    gemm_sm_k<<<dim3(M_ROWS/16, 2), 1024, 0, stream>>>(
        xsp, ysp, wvb, wtb, b_fc2_v, b_fc2_t, wvec, (float*)d_out);
}